// Round 16
// baseline (2220.458 us; speedup 1.0000x reference)
//
#include <hip/hip_runtime.h>

typedef _Float16 f16;
typedef _Float16 f16x8 __attribute__((ext_vector_type(8)));
typedef float f32x4 __attribute__((ext_vector_type(4)));

#define B_ 4096
#define N_ 32768
#define D_ 1024
#define BM 32
#define BN 256          // KV tile per iteration (16 cols per wave x 16 waves)
#define THREADS 1024    // 16 waves, 1 block/CU, 4 waves/SIMD
#define DSLICE 64       // D columns owned per wave in PV
#define NHALF (N_ / 2)
#define ITERS (NHALF / BN)   // 64

__device__ __forceinline__ f32x4 mfma16(f16x8 a, f16x8 b, f32x4 c) {
    return __builtin_amdgcn_mfma_f32_16x16x32_f16(a, b, c, 0, 0, 0);
}

// ---- K -> fragment-order f16 --------------------------------------------------
// Group (rb, ks): 16 K-rows x 32 k-cols; lane (lg*16+l15) holds
// K[rb*16+l15][ks*32+lg*8 .. +8].  Kf[((rb*32+ks)*64+lane)*8]
// -> hot-loop load = base + lane*16B: one contiguous 1KB wave-load.
__global__ void conv_kf(const float* __restrict__ K, f16* __restrict__ Kf) {
    int tid = blockIdx.x * 256 + threadIdx.x;       // < N_*D_/8
    int g = tid >> 6, lane = tid & 63;
    int rb = g >> 5, ks = g & 31;
    int l15 = lane & 15, lg = lane >> 4;
    const float* s = K + (size_t)(rb * 16 + l15) * D_ + ks * 32 + lg * 8;
    float4 a = *(const float4*)s, b = *(const float4*)(s + 4);
    f16x8 h;
    h[0] = (f16)a.x; h[1] = (f16)a.y; h[2] = (f16)a.z; h[3] = (f16)a.w;
    h[4] = (f16)b.x; h[5] = (f16)b.y; h[6] = (f16)b.z; h[7] = (f16)b.w;
    *(f16x8*)(Kf + (size_t)tid * 8) = h;
}

// ---- V -> fragment-order f16 (PV B-operand) -----------------------------------
// Group (kb, db): 32 kv-rows x 16 d-cols; lane holds V[kb*32+lg*8+j][db*16+l15].
// Vf[((kb*64+db)*64+lane)*8]
__global__ void conv_vf(const float* __restrict__ V, f16* __restrict__ Vf) {
    int tid = blockIdx.x * 256 + threadIdx.x;       // < N_*D_/8
    int g = tid >> 6, lane = tid & 63;
    int db = g & 63, kb = g >> 6;
    int l15 = lane & 15, lg = lane >> 4;
    const float* s = V + (size_t)(kb * 32 + lg * 8) * D_ + db * 16 + l15;
    f16x8 h;
    #pragma unroll
    for (int j = 0; j < 8; ++j) h[j] = (f16)s[(size_t)j * D_];
    *(f16x8*)(Vf + (size_t)tid * 8) = h;
}

// ---- main fused attention kernel ----------------------------------------------
// 16 waves: QK wave owns 16 KV cols (strip = wave); PV wave owns 64 D-cols.
// k-major LDS for X/P: off(row,d) = (d>>5)*2048 + row*64 + ((d&31)>>3)*16 + (d&7)*2
// All global K/V loads are lane-contiguous 1KB wave-loads (fragment order).
// Single barrier/iter (Pl/red 2-deep); defer-max skips O-rescale.
__global__ __launch_bounds__(THREADS, 1)
void attn_main(const float* __restrict__ Xg, const f16* __restrict__ Kf,
               const f16* __restrict__ Vf, float* __restrict__ Opart,
               float* __restrict__ Mpart, float* __restrict__ Lpart)
{
    __shared__ __align__(16) f16 Xh[BM * D_];     // 64 KB, k-major
    __shared__ __align__(16) f16 Pl[2][BM * BN];  // 2 x 16 KB, k-major
    __shared__ float2 red[2][BM][17];             // 2 x 4.25 KB, padded

    const int xcd   = blockIdx.x & 7;
    const int chunk = xcd >> 2;
    const int bblk  = ((blockIdx.x >> 3) << 2) | (xcd & 3);
    const int kvbase = chunk * NHALF;
    const int b0 = bblk * BM;
    const int t  = threadIdx.x;

    // --- stage X: fp32 -> f16 into k-major LDS ---
    for (int c = t; c < BM * D_ / 8; c += THREADS) {
        int dblk = c >> 7;
        int row  = (c >> 2) & 31;
        int sub  = c & 3;
        int d0   = dblk * 32 + sub * 8;
        const float* s = Xg + (size_t)(b0 + row) * D_ + d0;
        float4 a = *(const float4*)s, b = *(const float4*)(s + 4);
        f16x8 hi;
        hi[0] = (f16)a.x; hi[1] = (f16)a.y; hi[2] = (f16)a.z; hi[3] = (f16)a.w;
        hi[4] = (f16)b.x; hi[5] = (f16)b.y; hi[6] = (f16)b.z; hi[7] = (f16)b.w;
        *(f16x8*)((char*)Xh + dblk * 2048 + row * 64 + sub * 16) = hi;
    }
    __syncthreads();

    const int wave = t >> 6, lane = t & 63;
    const int l15 = lane & 15, lg = lane >> 4;

    const char* bh0 = (const char*)Xh + l15 * 64 + lg * 16;          // rows 0-15
    const char* bh1 = (const char*)Xh + (l15 + 16) * 64 + lg * 16;   // rows 16-31
    const char* pr0 = (const char*)&Pl[0][0] + l15 * 64 + lg * 16;
    const char* pr1 = (const char*)&Pl[0][0] + (l15 + 16) * 64 + lg * 16;

    // K fragment pointer: wave's 16-col strip = row-block (rb0 + wave).
    const f16* kp = Kf + ((size_t)(kvbase / 16 + wave) * 2048 + lane) * 8;
    // V fragment pointer: wave owns db = wave*4 .. +3.
    const f16* vbase = Vf + (((size_t)(kvbase / 32) * 64 + wave * 4) * 64 + lane) * 8;

    f32x4 S0, S1;
    f16x8 kA[2], kB[2];
    int pb = 0, pbOfs = 0;

    auto LOADK = [&](f16x8* buf, int ks0) {
        buf[0] = *(const f16x8*)(kp + (ks0    ) * 512);
        buf[1] = *(const f16x8*)(kp + (ks0 + 1) * 512);
    };
    auto USEK = [&](const f16x8* kb2, int ks0) {
        #pragma unroll
        for (int j = 0; j < 2; ++j) {
            int ks = ks0 + j;
            f16x8 ah0 = *(const f16x8*)(bh0 + ks * 2048);
            f16x8 ah1 = *(const f16x8*)(bh1 + ks * 2048);
            __builtin_amdgcn_s_setprio(1);
            S0 = mfma16(ah0, kb2[j], S0);
            S1 = mfma16(ah1, kb2[j], S1);
            __builtin_amdgcn_s_setprio(0);
        }
    };
    auto QK = [&]() {
        S0 = (f32x4){0.f, 0.f, 0.f, 0.f};
        S1 = (f32x4){0.f, 0.f, 0.f, 0.f};
        LOADK(kA, 0);
        LOADK(kB, 2);  USEK(kA, 0);
        LOADK(kA, 4);  USEK(kB, 2);
        LOADK(kB, 6);  USEK(kA, 4);
        LOADK(kA, 8);  USEK(kB, 6);
        LOADK(kB, 10); USEK(kA, 8);
        LOADK(kA, 12); USEK(kB, 10);
        LOADK(kB, 14); USEK(kA, 12);
        LOADK(kA, 16); USEK(kB, 14);
        LOADK(kB, 18); USEK(kA, 16);
        LOADK(kA, 20); USEK(kB, 18);
        LOADK(kB, 22); USEK(kA, 20);
        LOADK(kA, 24); USEK(kB, 22);
        LOADK(kB, 26); USEK(kA, 24);
        LOADK(kA, 28); USEK(kB, 26);
        LOADK(kB, 30); USEK(kA, 28);
                       USEK(kB, 30);
    };

    f32x4 O[2][4];
    #pragma unroll
    for (int rg = 0; rg < 2; ++rg)
        #pragma unroll
        for (int fn = 0; fn < 4; ++fn) O[rg][fn] = (f32x4){0.f, 0.f, 0.f, 0.f};
    float mq[8];
    #pragma unroll
    for (int u = 0; u < 8; ++u) mq[u] = -INFINITY;
    float m2a = -INFINITY, m2b = -INFINITY, l2a = 0.f, l2b = 0.f;

    f16x8 vA[4], vB[4];
    auto LOADV = [&](f16x8* buf, int ks2) {
        #pragma unroll
        for (int fn = 0; fn < 4; ++fn)
            buf[fn] = *(const f16x8*)(vbase + ks2 * 32768 + fn * 512);
    };
    // beta recomputed from red (no register cache): strip = ks2*2 + (lg>>1)
    auto USEV = [&](const f16x8* vb2, int ks2) {
        int strip = ks2 * 2 + (lg >> 1);
        f16 ba16 = (f16)__expf(red[pb][l15][strip].x - m2a);
        f16 bb16 = (f16)__expf(red[pb][l15 + 16][strip].x - m2b);
        f16x8 pa0 = *(const f16x8*)(pr0 + pbOfs + ks2 * 2048);
        f16x8 pa1 = *(const f16x8*)(pr1 + pbOfs + ks2 * 2048);
        #pragma unroll
        for (int j = 0; j < 8; ++j) { pa0[j] *= ba16; pa1[j] *= bb16; }
        __builtin_amdgcn_s_setprio(1);
        #pragma unroll
        for (int fn = 0; fn < 4; ++fn) {
            O[0][fn] = mfma16(pa0, vb2[fn], O[0][fn]);
            O[1][fn] = mfma16(pa1, vb2[fn], O[1][fn]);
        }
        __builtin_amdgcn_s_setprio(0);
    };

    QK();   // tile 0

    for (int it = 0; it < ITERS; ++it) {
        // ---- strip softmax over own 16 cols; publish P + {m,s} ----
        #pragma unroll
        for (int rg = 0; rg < 2; ++rg)
            #pragma unroll
            for (int i = 0; i < 4; ++i) {
                float v = rg ? S1[i] : S0[i];
                float mx = v;
                mx = fmaxf(mx, __shfl_xor(mx, 1));
                mx = fmaxf(mx, __shfl_xor(mx, 2));
                mx = fmaxf(mx, __shfl_xor(mx, 4));
                mx = fmaxf(mx, __shfl_xor(mx, 8));
                float p = __expf(v - mx);
                float s = p;
                s += __shfl_xor(s, 1);
                s += __shfl_xor(s, 2);
                s += __shfl_xor(s, 4);
                s += __shfl_xor(s, 8);
                int m = rg * 16 + lg * 4 + i;
                int off = pb * 16384 + (wave >> 1) * 2048 + m * 64
                        + ((wave & 1) * 2 + (l15 >> 3)) * 16 + ((l15 & 7) << 1);
                *(f16*)((char*)&Pl[0][0] + off) = (f16)p;
                if (l15 == 0) red[pb][m][wave] = make_float2(mx, s);
            }
        __syncthreads();        // the ONLY barrier in the loop

        pbOfs = pb * 16384;

        // ---- V prefetch: combine-VALU below covers the latency ----
        LOADV(vA, 0);
        LOADV(vB, 1);

        // ---- combine: global row max over 16 strips, l update ----
        float m2a0 = m2a, m2b0 = m2b;
        float M2an = m2a, M2bn = m2b;
        #pragma unroll
        for (int s2 = 0; s2 < 16; ++s2) {
            M2an = fmaxf(M2an, red[pb][l15][s2].x);
            M2bn = fmaxf(M2bn, red[pb][l15 + 16][s2].x);
        }
        float laa = 0.f, lbb = 0.f;
        #pragma unroll
        for (int s2 = 0; s2 < 16; ++s2) {
            float2 ra = red[pb][l15][s2], rb = red[pb][l15 + 16][s2];
            laa += __expf(ra.x - M2an) * ra.y;
            lbb += __expf(rb.x - M2bn) * rb.y;
        }
        l2a = l2a * __expf(m2a0 - M2an) + laa; m2a = M2an;
        l2b = l2b * __expf(m2b0 - M2bn) + lbb; m2b = M2bn;

        // ---- defer-max: only rescale O when some row max actually rose ----
        if (__any((M2an > m2a0) || (M2bn > m2b0))) {
            float al[2][4];
            #pragma unroll
            for (int rg = 0; rg < 2; ++rg)
                #pragma unroll
                for (int i = 0; i < 4; ++i) {
                    int u = rg * 4 + i;
                    int src = (lane & 48) | (lg * 4 + i);
                    float Mq = __shfl(rg ? M2bn : M2an, src);
                    al[rg][i] = __expf(mq[u] - Mq);
                    mq[u] = Mq;
                }
            #pragma unroll
            for (int rg = 0; rg < 2; ++rg)
                #pragma unroll
                for (int fn = 0; fn < 4; ++fn)
                    #pragma unroll
                    for (int i = 0; i < 4; ++i)
                        O[rg][fn][i] *= al[rg][i];
        }

        // ---- PV with double-buffered V registers (8 k-slices) ----
        USEV(vA, 0);  LOADV(vA, 2);
        USEV(vB, 1);  LOADV(vB, 3);
        USEV(vA, 2);  LOADV(vA, 4);
        USEV(vB, 3);  LOADV(vB, 5);
        USEV(vA, 4);  LOADV(vA, 6);
        USEV(vB, 5);  LOADV(vB, 7);
        USEV(vA, 6);
        USEV(vB, 7);

        // ---- advance; next tile's QK; flip P buffer (no closing barrier) ----
        kp += (size_t)16 * 16384;
        vbase += (size_t)8 * 32768;
        if (it + 1 < ITERS) QK();
        pb ^= 1;
    }

    // ---- epilogue: unnormalized O + per-row m/l partials ----
    float* Op = Opart + (size_t)chunk * B_ * D_;
    #pragma unroll
    for (int rg = 0; rg < 2; ++rg)
        #pragma unroll
        for (int fn = 0; fn < 4; ++fn)
            #pragma unroll
            for (int i = 0; i < 4; ++i) {
                int row = b0 + rg * 16 + lg * 4 + i;
                int col = wave * DSLICE + fn * 16 + l15;
                Op[(size_t)row * D_ + col] = O[rg][fn][i];
            }
    if (wave == 0 && lg == 0) {
        Mpart[(size_t)chunk * B_ + b0 + l15]      = m2a;
        Lpart[(size_t)chunk * B_ + b0 + l15]      = l2a;
        Mpart[(size_t)chunk * B_ + b0 + 16 + l15] = m2b;
        Lpart[(size_t)chunk * B_ + b0 + 16 + l15] = l2b;
    }
}

// ---- combine NSPLIT=2 partials -------------------------------------------------
__global__ void combine_k(const float* __restrict__ Opart,
                          const float* __restrict__ Mp, const float* __restrict__ Lp,
                          float* __restrict__ Outg)
{
    int b = blockIdx.x;
    float m0 = Mp[b], m1 = Mp[B_ + b];
    float l0 = Lp[b], l1 = Lp[B_ + b];
    float M  = fmaxf(m0, m1);
    float w0 = __expf(m0 - M), w1 = __expf(m1 - M);
    float inv = 1.f / (w0 * l0 + w1 * l1);
    const float4* O0 = (const float4*)(Opart + (size_t)b * D_);
    const float4* O1 = (const float4*)(Opart + (size_t)B_ * D_ + (size_t)b * D_);
    float4* o = (float4*)(Outg + (size_t)b * D_);
    for (int i = threadIdx.x; i < D_ / 4; i += blockDim.x) {
        float4 a = O0[i], c = O1[i];
        float4 r;
        r.x = (w0 * a.x + w1 * c.x) * inv;
        r.y = (w0 * a.y + w1 * c.y) * inv;
        r.z = (w0 * a.z + w1 * c.z) * inv;
        r.w = (w0 * a.w + w1 * c.w) * inv;
        o[i] = r;
    }
}

extern "C" void kernel_launch(void* const* d_in, const int* in_sizes, int n_in,
                              void* d_out, int out_size, void* d_ws, size_t ws_size,
                              hipStream_t stream) {
    const float* X = (const float*)d_in[0];
    const float* K = (const float*)d_in[1];
    const float* V = (const float*)d_in[2];
    float* Out = (float*)d_out;

    const size_t szKf = (size_t)N_ * D_ * sizeof(f16);   // 64 MiB
    const size_t szVf = (size_t)N_ * D_ * sizeof(f16);   // 64 MiB
    const size_t szOp = 2ull * B_ * D_ * sizeof(float);  // 32 MiB
    const size_t szM  = 2ull * B_ * sizeof(float);

    f16*   Kf = (f16*)d_ws;
    f16*   Vf = (f16*)((char*)d_ws + szKf);
    float* Op = (float*)((char*)d_ws + szKf + szVf);
    float* Mp = (float*)((char*)Op + szOp);
    float* Lp = (float*)((char*)Mp + szM);

    conv_kf<<<(N_ * D_ / 8) / 256, 256, 0, stream>>>(K, Kf);
    conv_vf<<<(N_ * D_ / 8) / 256, 256, 0, stream>>>(V, Vf);
    attn_main<<<256, THREADS, 0, stream>>>(X, Kf, Vf, Op, Mp, Lp);
    combine_k<<<B_, 256, 0, stream>>>(Op, Mp, Lp, Out);
}

// Round 17
// 876.318 us; speedup vs baseline: 2.5339x; 2.5339x over previous
//
#include <hip/hip_runtime.h>

typedef _Float16 f16;
typedef _Float16 f16x8 __attribute__((ext_vector_type(8)));
typedef float f32x4 __attribute__((ext_vector_type(4)));

#define B_ 4096
#define N_ 32768
#define D_ 1024
#define BM 32
#define BN 256          // KV tile per iteration (32 cols per wave x 8 waves)
#define THREADS 512
#define DSLICE 128      // D columns owned per wave in PV
#define NHALF (N_ / 2)
#define ITERS (NHALF / BN)   // 64

__device__ __forceinline__ f32x4 mfma16(f16x8 a, f16x8 b, f32x4 c) {
    return __builtin_amdgcn_mfma_f32_16x16x32_f16(a, b, c, 0, 0, 0);
}

// ---- K -> fragment-order f16 --------------------------------------------------
// Group (rb, ks): 16 K-rows x 32 k-cols; lane (lg*16+l15) holds
// K[rb*16+l15][ks*32+lg*8 .. +8].  Kf[((rb*32+ks)*64+lane)*8]
// -> hot-loop load = base + lane*16B: one contiguous 1KB wave-load.
__global__ void conv_kf(const float* __restrict__ K, f16* __restrict__ Kf) {
    int tid = blockIdx.x * 256 + threadIdx.x;       // < N_*D_/8
    int g = tid >> 6, lane = tid & 63;
    int rb = g >> 5, ks = g & 31;
    int l15 = lane & 15, lg = lane >> 4;
    const float* s = K + (size_t)(rb * 16 + l15) * D_ + ks * 32 + lg * 8;
    float4 a = *(const float4*)s, b = *(const float4*)(s + 4);
    f16x8 h;
    h[0] = (f16)a.x; h[1] = (f16)a.y; h[2] = (f16)a.z; h[3] = (f16)a.w;
    h[4] = (f16)b.x; h[5] = (f16)b.y; h[6] = (f16)b.z; h[7] = (f16)b.w;
    *(f16x8*)(Kf + (size_t)tid * 8) = h;
}

// ---- V -> fragment-order f16 (PV B-operand) -----------------------------------
// Group (kb, db): 32 kv-rows x 16 d-cols; lane holds V[kb*32+lg*8+j][db*16+l15].
// Vf[((kb*64+db)*64+lane)*8]
__global__ void conv_vf(const float* __restrict__ V, f16* __restrict__ Vf) {
    int tid = blockIdx.x * 256 + threadIdx.x;       // < N_*D_/8
    int g = tid >> 6, lane = tid & 63;
    int db = g & 63, kb = g >> 6;
    int l15 = lane & 15, lg = lane >> 4;
    const float* s = V + (size_t)(kb * 32 + lg * 8) * D_ + db * 16 + l15;
    f16x8 h;
    #pragma unroll
    for (int j = 0; j < 8; ++j) h[j] = (f16)s[(size_t)j * D_];
    *(f16x8*)(Vf + (size_t)tid * 8) = h;
}

// ---- main fused attention kernel ----------------------------------------------
// k-major LDS for X/P: off(row,d) = (d>>5)*2048 + row*64 + ((d&31)>>3)*16 + (d&7)*2
// All global K/V loads are lane-contiguous 1KB wave-loads (fragment order).
// SINGLE barrier per iteration via 2-deep Pl/red double-buffer: barrier-release
// arithmetic bounds wave skew to one loop body, so write(pb^1) never races
// read(pb).  Defer-max: skip alpha/exp/O-rescale when no row max increased.
__global__ __launch_bounds__(THREADS, 2)
void attn_main(const float* __restrict__ Xg, const f16* __restrict__ Kf,
               const f16* __restrict__ Vf, float* __restrict__ Opart,
               float* __restrict__ Mpart, float* __restrict__ Lpart)
{
    __shared__ __align__(16) f16 Xh[BM * D_];     // 64 KB, k-major
    __shared__ __align__(16) f16 Pl[2][BM * BN];  // 2 x 16 KB, k-major
    __shared__ float2 red[2][BM][9];              // 2 x 2.3 KB, padded

    const int xcd   = blockIdx.x & 7;
    const int chunk = xcd >> 2;
    const int bblk  = ((blockIdx.x >> 3) << 2) | (xcd & 3);
    const int kvbase = chunk * NHALF;
    const int b0 = bblk * BM;
    const int t  = threadIdx.x;

    // --- stage X: fp32 -> f16 into k-major LDS ---
    for (int c = t; c < BM * D_ / 8; c += THREADS) {
        int dblk = c >> 7;
        int row  = (c >> 2) & 31;
        int sub  = c & 3;
        int d0   = dblk * 32 + sub * 8;
        const float* s = Xg + (size_t)(b0 + row) * D_ + d0;
        float4 a = *(const float4*)s, b = *(const float4*)(s + 4);
        f16x8 hi;
        hi[0] = (f16)a.x; hi[1] = (f16)a.y; hi[2] = (f16)a.z; hi[3] = (f16)a.w;
        hi[4] = (f16)b.x; hi[5] = (f16)b.y; hi[6] = (f16)b.z; hi[7] = (f16)b.w;
        *(f16x8*)((char*)Xh + dblk * 2048 + row * 64 + sub * 16) = hi;
    }
    __syncthreads();

    const int wave = t >> 6, lane = t & 63;
    const int l15 = lane & 15, lg = lane >> 4;

    const char* bh0 = (const char*)Xh + l15 * 64 + lg * 16;
    const char* bh1 = (const char*)Xh + (l15 + 16) * 64 + lg * 16;
    const char* pr0 = (const char*)&Pl[0][0] + l15 * 64 + lg * 16;
    const char* pr1 = (const char*)&Pl[0][0] + (l15 + 16) * 64 + lg * 16;

    // K fragment pointers: per-ks stride 512 f16; kp1 = next row-block.
    const f16* kp0 = Kf + ((size_t)(kvbase / 16 + wave * 2) * 32 * 64 + lane) * 8;
    const f16* kp1 = kp0 + 16384;
    // V fragment pointer: wave owns db = wave*8 .. +7.
    const f16* vbase = Vf + (((size_t)(kvbase / 32) * 64 + wave * 8) * 64 + lane) * 8;

    f32x4 S[2][2];
    f16x8 kA[8], kB[8];
    int pbOfs = 0;

    auto LOADK = [&](f16x8* buf, int ks0) {
        #pragma unroll
        for (int j = 0; j < 4; ++j) {
            buf[2 * j]     = *(const f16x8*)(kp0 + (ks0 + j) * 512);
            buf[2 * j + 1] = *(const f16x8*)(kp1 + (ks0 + j) * 512);
        }
    };
    auto USEK = [&](const f16x8* kb2, int ks0) {
        #pragma unroll
        for (int j = 0; j < 4; ++j) {
            int ks = ks0 + j;
            f16x8 ah0 = *(const f16x8*)(bh0 + ks * 2048);
            f16x8 ah1 = *(const f16x8*)(bh1 + ks * 2048);
            __builtin_amdgcn_s_setprio(1);
            S[0][0] = mfma16(ah0, kb2[2 * j],     S[0][0]);
            S[0][1] = mfma16(ah0, kb2[2 * j + 1], S[0][1]);
            S[1][0] = mfma16(ah1, kb2[2 * j],     S[1][0]);
            S[1][1] = mfma16(ah1, kb2[2 * j + 1], S[1][1]);
            __builtin_amdgcn_s_setprio(0);
        }
    };
    auto QK = [&]() {
        #pragma unroll
        for (int rg = 0; rg < 2; ++rg)
            #pragma unroll
            for (int cg = 0; cg < 2; ++cg) S[rg][cg] = (f32x4){0.f, 0.f, 0.f, 0.f};
        LOADK(kA, 0);
        LOADK(kB, 4);  USEK(kA, 0);
        LOADK(kA, 8);  USEK(kB, 4);
        LOADK(kB, 12); USEK(kA, 8);
        LOADK(kA, 16); USEK(kB, 12);
        LOADK(kB, 20); USEK(kA, 16);
        LOADK(kA, 24); USEK(kB, 20);
        LOADK(kB, 28); USEK(kA, 24);
                       USEK(kB, 28);
    };

    f32x4 O[2][8];
    #pragma unroll
    for (int rg = 0; rg < 2; ++rg)
        #pragma unroll
        for (int fn = 0; fn < 8; ++fn) O[rg][fn] = (f32x4){0.f, 0.f, 0.f, 0.f};
    float mq[8];
    #pragma unroll
    for (int u = 0; u < 8; ++u) mq[u] = -INFINITY;
    float m2a = -INFINITY, m2b = -INFINITY, l2a = 0.f, l2b = 0.f;

    f16x8 vA[8], vB[8];
    auto LOADV = [&](f16x8* buf, int ks2) {
        #pragma unroll
        for (int fn = 0; fn < 8; ++fn)
            buf[fn] = *(const f16x8*)(vbase + ks2 * 32768 + fn * 512);
    };
    float ba[8], bb[8];
    auto USEV = [&](const f16x8* vb2, int ks2) {
        f16 ba16 = (f16)ba[ks2], bb16 = (f16)bb[ks2];
        f16x8 pa0 = *(const f16x8*)(pr0 + pbOfs + ks2 * 2048);
        f16x8 pa1 = *(const f16x8*)(pr1 + pbOfs + ks2 * 2048);
        #pragma unroll
        for (int j = 0; j < 8; ++j) { pa0[j] *= ba16; pa1[j] *= bb16; }
        __builtin_amdgcn_s_setprio(1);
        #pragma unroll
        for (int fn = 0; fn < 8; ++fn) {
            O[0][fn] = mfma16(pa0, vb2[fn], O[0][fn]);
            O[1][fn] = mfma16(pa1, vb2[fn], O[1][fn]);
        }
        __builtin_amdgcn_s_setprio(0);
    };

    QK();   // tile 0
    int pb = 0;

    for (int it = 0; it < ITERS; ++it) {
        // ---- strip softmax: max, exp, sum over own 32 cols; publish P + {m,s} ----
        #pragma unroll
        for (int rg = 0; rg < 2; ++rg)
            #pragma unroll
            for (int i = 0; i < 4; ++i) {
                float a = S[rg][0][i], b = S[rg][1][i];
                float mx = fmaxf(a, b);
                mx = fmaxf(mx, __shfl_xor(mx, 1));
                mx = fmaxf(mx, __shfl_xor(mx, 2));
                mx = fmaxf(mx, __shfl_xor(mx, 4));
                mx = fmaxf(mx, __shfl_xor(mx, 8));
                float p0 = __expf(a - mx), p1 = __expf(b - mx);
                float s = p0 + p1;
                s += __shfl_xor(s, 1);
                s += __shfl_xor(s, 2);
                s += __shfl_xor(s, 4);
                s += __shfl_xor(s, 8);
                int m = rg * 16 + lg * 4 + i;
                int off0 = pb * 16384 + wave * 2048 + m * 64
                         + ((l15 >> 3) << 4) + ((l15 & 7) << 1);
                *(f16*)((char*)&Pl[0][0] + off0)      = (f16)p0;
                *(f16*)((char*)&Pl[0][0] + off0 + 32) = (f16)p1;
                if (l15 == 0) red[pb][m][wave] = make_float2(mx, s);
            }
        __syncthreads();        // the ONLY barrier in the loop

        pbOfs = pb * 16384;

        // ---- V prefetch: combine-VALU below covers the latency ----
        LOADV(vA, 0);
        LOADV(vB, 1);

        // ---- combine: global row max, beta per strip, l update ----
        float m2a0 = m2a, m2b0 = m2b;
        float M2an = m2a, M2bn = m2b;
        #pragma unroll
        for (int s2 = 0; s2 < 8; ++s2) {
            M2an = fmaxf(M2an, red[pb][l15][s2].x);
            M2bn = fmaxf(M2bn, red[pb][l15 + 16][s2].x);
        }
        float laa = 0.f, lbb = 0.f;
        #pragma unroll
        for (int s2 = 0; s2 < 8; ++s2) {
            float2 ra = red[pb][l15][s2], rb = red[pb][l15 + 16][s2];
            ba[s2] = __expf(ra.x - M2an); laa += ra.y * ba[s2];
            bb[s2] = __expf(rb.x - M2bn); lbb += rb.y * bb[s2];
        }
        l2a = l2a * __expf(m2a - M2an) + laa; m2a = M2an;
        l2b = l2b * __expf(m2b - M2bn) + lbb; m2b = M2bn;

        // ---- defer-max: only rescale O when some row max actually rose ----
        if (__any((M2an > m2a0) || (M2bn > m2b0))) {
            float al[2][4];
            #pragma unroll
            for (int rg = 0; rg < 2; ++rg)
                #pragma unroll
                for (int i = 0; i < 4; ++i) {
                    int u = rg * 4 + i;
                    int src = (lane & 48) | (lg * 4 + i);
                    float Mq = __shfl(rg ? M2bn : M2an, src);
                    al[rg][i] = __expf(mq[u] - Mq);
                    mq[u] = Mq;
                }
            #pragma unroll
            for (int rg = 0; rg < 2; ++rg)
                #pragma unroll
                for (int fn = 0; fn < 8; ++fn)
                    #pragma unroll
                    for (int i = 0; i < 4; ++i)
                        O[rg][fn][i] *= al[rg][i];
        }

        // ---- PV with double-buffered V registers ----
        USEV(vA, 0);  LOADV(vA, 2);
        USEV(vB, 1);  LOADV(vB, 3);
        USEV(vA, 2);  LOADV(vA, 4);
        USEV(vB, 3);  LOADV(vB, 5);
        USEV(vA, 4);  LOADV(vA, 6);
        USEV(vB, 5);  LOADV(vB, 7);
        USEV(vA, 6);
        USEV(vB, 7);

        // ---- advance; next tile's QK; flip P buffer (no closing barrier) ----
        kp0 += (size_t)16 * 16384;
        kp1 += (size_t)16 * 16384;
        vbase += (size_t)8 * 32768;
        if (it + 1 < ITERS) QK();
        pb ^= 1;
    }

    // ---- epilogue: unnormalized O + per-row m/l partials ----
    float* Op = Opart + (size_t)chunk * B_ * D_;
    #pragma unroll
    for (int rg = 0; rg < 2; ++rg)
        #pragma unroll
        for (int fn = 0; fn < 8; ++fn)
            #pragma unroll
            for (int i = 0; i < 4; ++i) {
                int row = b0 + rg * 16 + lg * 4 + i;
                int col = wave * DSLICE + fn * 16 + l15;
                Op[(size_t)row * D_ + col] = O[rg][fn][i];
            }
    if (wave == 0 && lg == 0) {
        Mpart[(size_t)chunk * B_ + b0 + l15]      = m2a;
        Lpart[(size_t)chunk * B_ + b0 + l15]      = l2a;
        Mpart[(size_t)chunk * B_ + b0 + 16 + l15] = m2b;
        Lpart[(size_t)chunk * B_ + b0 + 16 + l15] = l2b;
    }
}

// ---- combine NSPLIT=2 partials -------------------------------------------------
__global__ void combine_k(const float* __restrict__ Opart,
                          const float* __restrict__ Mp, const float* __restrict__ Lp,
                          float* __restrict__ Outg)
{
    int b = blockIdx.x;
    float m0 = Mp[b], m1 = Mp[B_ + b];
    float l0 = Lp[b], l1 = Lp[B_ + b];
    float M  = fmaxf(m0, m1);
    float w0 = __expf(m0 - M), w1 = __expf(m1 - M);
    float inv = 1.f / (w0 * l0 + w1 * l1);
    const float4* O0 = (const float4*)(Opart + (size_t)b * D_);
    const float4* O1 = (const float4*)(Opart + (size_t)B_ * D_ + (size_t)b * D_);
    float4* o = (float4*)(Outg + (size_t)b * D_);
    for (int i = threadIdx.x; i < D_ / 4; i += blockDim.x) {
        float4 a = O0[i], c = O1[i];
        float4 r;
        r.x = (w0 * a.x + w1 * c.x) * inv;
        r.y = (w0 * a.y + w1 * c.y) * inv;
        r.z = (w0 * a.z + w1 * c.z) * inv;
        r.w = (w0 * a.w + w1 * c.w) * inv;
        o[i] = r;
    }
}

extern "C" void kernel_launch(void* const* d_in, const int* in_sizes, int n_in,
                              void* d_out, int out_size, void* d_ws, size_t ws_size,
                              hipStream_t stream) {
    const float* X = (const float*)d_in[0];
    const float* K = (const float*)d_in[1];
    const float* V = (const float*)d_in[2];
    float* Out = (float*)d_out;

    const size_t szKf = (size_t)N_ * D_ * sizeof(f16);   // 64 MiB
    const size_t szVf = (size_t)N_ * D_ * sizeof(f16);   // 64 MiB
    const size_t szOp = 2ull * B_ * D_ * sizeof(float);  // 32 MiB
    const size_t szM  = 2ull * B_ * sizeof(float);

    f16*   Kf = (f16*)d_ws;
    f16*   Vf = (f16*)((char*)d_ws + szKf);
    float* Op = (float*)((char*)d_ws + szKf + szVf);
    float* Mp = (float*)((char*)Op + szOp);
    float* Lp = (float*)((char*)Mp + szM);

    conv_kf<<<(N_ * D_ / 8) / 256, 256, 0, stream>>>(K, Kf);
    conv_vf<<<(N_ * D_ / 8) / 256, 256, 0, stream>>>(V, Vf);
    attn_main<<<256, THREADS, 0, stream>>>(X, Kf, Vf, Op, Mp, Lp);
    combine_k<<<B_, 256, 0, stream>>>(Op, Mp, Lp, Out);
}